// Round 5
// baseline (206.955 us; speedup 1.0000x reference)
//
#include <hip/hip_runtime.h>

// EMA chunked scan + inverse-gather broadcast for DeChunkLayer (R14).
// R14 = R13 (stateless fused, 204.2 us) + ONE variable: 512 threads/block
// (v2f per thread) instead of 256 (v4f). Grid stays 512 (1 block/chunk).
//
// Theory: every version since R12 shows Occupancy ~20%, VALUBusy 3%, kernel
// HBM ~1.6 TB/s while the writes-only fill hits 6.9 TB/s. 512 blocks x 256
// thr = 2 blocks/CU = 8 waves/CU (2/SIMD) — request-queue starvation: too
// few outstanding loads/stores to cover ~900cy HBM latency in every phase
// (x loads, b sweeps, NT store drain). This limiter is shared by R11's
// K1/K2 (same geometry), which is why fusion-vs-split kept being noise.
// 512 thr/block -> 16 waves/CU (4/SIMD), 2x in-flight memory ops; 8 B/lane
// float2 access stays in the coalescing sweet spot. launch_bounds(512,4)
// = 2 blocks/CU, VGPR cap 128 (kernel needs ~60).
// Predict: occupancy ~20->~40%, kernel HBM 1.6->>=3 TB/s, kernel ~75->45-55
// => dur 204.2 -> ~175-185 (beats R11 198.6). Null => store-drain bound ->
// probe cached stores / R11-with-512thr-K2 next.
//
// x: (1, 16384, 1024) f32, p_selected: (16384,) f32, b: (1, 32768) i32
// out: (1, 32768, 1024) f32
// z_t = (1-p_t) z_{t-1} + p_t x_t  (p clipped to [1e-4, 1-1e-4])
// out[f] = z[t] for f in [pos[t], pos[t+1])

#define DCH 1024
#define L_COMP 16384
#define L_FULL 32768
#define CHUNK 32
#define NCHUNK (L_COMP / CHUNK)   // 512
#define SEG (L_FULL / NCHUNK)     // 64 b-elements per segment
#define NTHR 512
#define EPSV 1e-4f
#define WMIN 1e-12f               // ~2^-40 lookback window (matches R11-R13)

typedef float v2f __attribute__((ext_vector_type(2)));

__device__ __forceinline__ float clipp(float p) {
    p = fmaxf(p, EPSV);
    return fminf(p, 1.0f - EPSV);
}

__global__ __launch_bounds__(NTHR, 4) void fused_kernel(
    const float* __restrict__ x, const float* __restrict__ p,
    const int* __restrict__ b, float* __restrict__ out) {
    const int c = blockIdx.x;
    const int tid = threadIdx.x;
    const int lane = tid & 63;
    const int wave = tid >> 6;          // 0..7
    const int base = c * CHUNK;

    __shared__ int bpref[NCHUNK + 1];
    __shared__ int spos[CHUNK + 1];
    __shared__ int wtot[8];

    // (a) redundant b popcount + exclusive prefix over 512 segments.
    //     One segment per thread: 16 int4 loads (L2-warm).
    {
        const int4* bseg = reinterpret_cast<const int4*>(b) + tid * (SEG / 4);
        int v = 0;
#pragma unroll 4
        for (int q = 0; q < SEG / 4; ++q) {
            int4 w = bseg[q];
            v += w.x + w.y + w.z + w.w;
        }
        int incl = v;
#pragma unroll
        for (int off = 1; off < 64; off <<= 1) {
            int n = __shfl_up(incl, off, 64);
            if (lane >= off) incl += n;
        }
        if (lane == 63) wtot[wave] = incl;
        __syncthreads();
        int woff = 0;
        for (int w = 0; w < wave; ++w) woff += wtot[w];
        bpref[tid] = woff + incl - v;   // exclusive prefix
        if (tid == 0) bpref[NCHUNK] = L_COMP;
        __syncthreads();
    }

    // (b) rank-select this chunk's 33 pos values (threads 0..32)
    if (tid <= CHUNK) {
        int t = base + tid; // global one-rank (0-indexed)
        int posv = L_FULL;
        if (t < L_COMP) {
            int lo = 0, hi = NCHUNK;
            while (hi - lo > 1) {
                int mid = (lo + hi) >> 1;
                if (bpref[mid] <= t) lo = mid; else hi = mid;
            }
            int lr = t - bpref[lo]; // local rank within segment lo
            const int4* bseg = reinterpret_cast<const int4*>(b) + lo * (SEG / 4);
            int cnt = 0;
#pragma unroll 4
            for (int q = 0; q < SEG / 4; ++q) {
                int4 w = bseg[q];
                if (w.x) { if (cnt == lr) posv = lo * SEG + 4 * q + 0; ++cnt; }
                if (w.y) { if (cnt == lr) posv = lo * SEG + 4 * q + 1; ++cnt; }
                if (w.z) { if (cnt == lr) posv = lo * SEG + 4 * q + 2; ++cnt; }
                if (w.w) { if (cnt == lr) posv = lo * SEG + 4 * q + 3; ++cnt; }
            }
        }
        spos[tid] = posv;
    }
    __syncthreads();

    // (c) window-find: walk chunk decay products backwards through p.
    //     Chunk k included iff prod_{j=k+1..c-1} A_j >= WMIN. Uniform scalar
    //     work, ~32*W mults; W~1 on bench; degrades to full replay worst-case.
    int kstart = c;
    {
        float w = 1.0f;
        while (kstart > 0 && w >= WMIN) {
            --kstart;
            float ap = 1.0f;
#pragma unroll 8
            for (int t = 0; t < CHUNK; ++t)
                ap *= (1.0f - clipp(p[kstart * CHUNK + t]));
            w *= ap;
        }
    }

    // (d) forward scan from row kstart*32 with h=0: warmup rows (no stores,
    //     x mostly L3-hit), then chunk c's rows with ranged NT broadcast.
    {
        const v2f* x2 = reinterpret_cast<const v2f*>(x) + tid;
        v2f h = (v2f)0.f;
        for (int r = kstart * CHUNK; r < base; r += 8) {
            v2f xv[8];
            float pv[8];
#pragma unroll
            for (int j = 0; j < 8; ++j) {
                xv[j] = x2[(size_t)(r + j) * (DCH / 2)];
                pv[j] = clipp(p[r + j]);            // uniform -> scalar
            }
#pragma unroll
            for (int j = 0; j < 8; ++j) {
                float a = 1.0f - pv[j];
                h = a * h + pv[j] * xv[j];
            }
        }
        v2f* out2 = reinterpret_cast<v2f*>(out) + tid;
        int f0 = spos[0];
        for (int ib = 0; ib < CHUNK; ib += 8) {
            v2f xv[8];
            float pv[8];
            int fe[8];
#pragma unroll
            for (int j = 0; j < 8; ++j) {
                xv[j] = x2[(size_t)(base + ib + j) * (DCH / 2)];
                pv[j] = clipp(p[base + ib + j]);    // uniform -> scalar
                fe[j] = spos[ib + j + 1];           // LDS
            }
#pragma unroll
            for (int j = 0; j < 8; ++j) {
                float a = 1.0f - pv[j];
                h = a * h + pv[j] * xv[j];
                for (int f = f0; f < fe[j]; ++f) {
                    __builtin_nontemporal_store(h, &out2[(size_t)f * (DCH / 2)]);
                }
                f0 = fe[j];
            }
        }
    }
}

extern "C" void kernel_launch(void* const* d_in, const int* in_sizes, int n_in,
                              void* d_out, int out_size, void* d_ws, size_t ws_size,
                              hipStream_t stream) {
    const float* x = (const float*)d_in[0];
    const float* p = (const float*)d_in[1];
    const int* b = (const int*)d_in[2];
    float* out = (float*)d_out;
    (void)d_ws; (void)ws_size;

    fused_kernel<<<NCHUNK, NTHR, 0, stream>>>(x, p, b, out);
}

// Round 6
// 205.020 us; speedup vs baseline: 1.0094x; 1.0094x over previous
//
#include <hip/hip_runtime.h>

// EMA chunked scan + inverse-gather broadcast for DeChunkLayer (R15).
// R15 = R14 (stateless fused 512thr, 207.0 us) + ONE variable: phase-split
// load/compute/store in phase (d) — whole own-chunk in registers.
//
// Theory: loads and stores share the per-wave vmcnt FIFO. R13/R14's inner
// loop interleaves {use xv[j] (s_waitcnt) ; NT-store rows} so every
// load-use wait queues behind store drains -> each wave self-serializes at
// store-drain latency, row by row. Explains: ~2.9 TB/s vs 6.3 copy ceiling,
// VALUBusy 3%, and BOTH occupancy probes null (R14: 2x waves no change —
// every wave stalls identically). Also retro-explains R9 (NT > cached:
// faster drain = shorter entangled waits).
// Fix: (d2) burst-load 32 rows into xv[32] v2f regs (pure loads, 32
// outstanding); (d3) in-place register scan (p via scalar/SMEM = lgkmcnt);
// (d4) pure NT-store burst that nothing waits on (no trailing barrier;
// drain overlaps the co-resident block's load phase). Warmup already
// load-only. VGPR ~100-115 < 128 cap (R12's spill was v4f=128 for xv;
// v2f halves it).
// Predict: VGPR 100-120 scratch 0; kernel ~70 -> 40-50 us => dur 207 ->
// ~175-188 (beats R11 198.6). Spill => fallback 16-row half-chunks.
// No-spill null => vmcnt theory wrong -> two-kernel pure-store K2 next.
//
// x: (1, 16384, 1024) f32, p_selected: (16384,) f32, b: (1, 32768) i32
// out: (1, 32768, 1024) f32
// z_t = (1-p_t) z_{t-1} + p_t x_t  (p clipped to [1e-4, 1-1e-4])
// out[f] = z[t] for f in [pos[t], pos[t+1])

#define DCH 1024
#define L_COMP 16384
#define L_FULL 32768
#define CHUNK 32
#define NCHUNK (L_COMP / CHUNK)   // 512
#define SEG (L_FULL / NCHUNK)     // 64 b-elements per segment
#define NTHR 512
#define EPSV 1e-4f
#define WMIN 1e-12f               // ~2^-40 lookback window (matches R11-R14)

typedef float v2f __attribute__((ext_vector_type(2)));

__device__ __forceinline__ float clipp(float p) {
    p = fmaxf(p, EPSV);
    return fminf(p, 1.0f - EPSV);
}

__global__ __launch_bounds__(NTHR, 4) void fused_kernel(
    const float* __restrict__ x, const float* __restrict__ p,
    const int* __restrict__ b, float* __restrict__ out) {
    const int c = blockIdx.x;
    const int tid = threadIdx.x;
    const int lane = tid & 63;
    const int wave = tid >> 6;          // 0..7
    const int base = c * CHUNK;

    __shared__ int bpref[NCHUNK + 1];
    __shared__ int spos[CHUNK + 1];
    __shared__ int wtot[8];

    // (a) redundant b popcount + exclusive prefix over 512 segments.
    //     One segment per thread: 16 int4 loads (L2-warm).
    {
        const int4* bseg = reinterpret_cast<const int4*>(b) + tid * (SEG / 4);
        int v = 0;
#pragma unroll 4
        for (int q = 0; q < SEG / 4; ++q) {
            int4 w = bseg[q];
            v += w.x + w.y + w.z + w.w;
        }
        int incl = v;
#pragma unroll
        for (int off = 1; off < 64; off <<= 1) {
            int n = __shfl_up(incl, off, 64);
            if (lane >= off) incl += n;
        }
        if (lane == 63) wtot[wave] = incl;
        __syncthreads();
        int woff = 0;
        for (int w = 0; w < wave; ++w) woff += wtot[w];
        bpref[tid] = woff + incl - v;   // exclusive prefix
        if (tid == 0) bpref[NCHUNK] = L_COMP;
        __syncthreads();
    }

    // (b) rank-select this chunk's 33 pos values (threads 0..32)
    if (tid <= CHUNK) {
        int t = base + tid; // global one-rank (0-indexed)
        int posv = L_FULL;
        if (t < L_COMP) {
            int lo = 0, hi = NCHUNK;
            while (hi - lo > 1) {
                int mid = (lo + hi) >> 1;
                if (bpref[mid] <= t) lo = mid; else hi = mid;
            }
            int lr = t - bpref[lo]; // local rank within segment lo
            const int4* bseg = reinterpret_cast<const int4*>(b) + lo * (SEG / 4);
            int cnt = 0;
#pragma unroll 4
            for (int q = 0; q < SEG / 4; ++q) {
                int4 w = bseg[q];
                if (w.x) { if (cnt == lr) posv = lo * SEG + 4 * q + 0; ++cnt; }
                if (w.y) { if (cnt == lr) posv = lo * SEG + 4 * q + 1; ++cnt; }
                if (w.z) { if (cnt == lr) posv = lo * SEG + 4 * q + 2; ++cnt; }
                if (w.w) { if (cnt == lr) posv = lo * SEG + 4 * q + 3; ++cnt; }
            }
        }
        spos[tid] = posv;
    }
    __syncthreads();

    // (c) window-find: walk chunk decay products backwards through p.
    //     Chunk k included iff prod_{j=k+1..c-1} A_j >= WMIN. Uniform scalar
    //     work; W~1 on bench; degrades to full replay worst-case.
    int kstart = c;
    {
        float w = 1.0f;
        while (kstart > 0 && w >= WMIN) {
            --kstart;
            float ap = 1.0f;
#pragma unroll 8
            for (int t = 0; t < CHUNK; ++t)
                ap *= (1.0f - clipp(p[kstart * CHUNK + t]));
            w *= ap;
        }
    }

    // (d1) warmup scan from row kstart*32 with h=0: pure loads, no stores.
    const v2f* x2 = reinterpret_cast<const v2f*>(x) + tid;
    v2f h = (v2f)0.f;
    for (int r = kstart * CHUNK; r < base; r += 8) {
        v2f xw[8];
        float pw[8];
#pragma unroll
        for (int j = 0; j < 8; ++j) {
            xw[j] = x2[(size_t)(r + j) * (DCH / 2)];
            pw[j] = clipp(p[r + j]);            // uniform -> scalar
        }
#pragma unroll
        for (int j = 0; j < 8; ++j) {
            float a = 1.0f - pw[j];
            h = a * h + pw[j] * xw[j];
        }
    }

    // (d2) burst-load the whole own chunk: 32 outstanding pure loads.
    v2f xv[CHUNK];   // 64 VGPR, static indexing only (rule #20)
#pragma unroll
    for (int j = 0; j < CHUNK; ++j)
        xv[j] = x2[(size_t)(base + j) * (DCH / 2)];

    // (d3) in-place register scan; p via uniform scalar path (lgkmcnt).
#pragma unroll
    for (int j = 0; j < CHUNK; ++j) {
        float pt = clipp(p[base + j]);
        float a = 1.0f - pt;
        h = a * h + pt * xv[j];
        xv[j] = h;
    }

    // (d4) pure NT-store burst; nothing ever waits on these stores.
    {
        v2f* out2 = reinterpret_cast<v2f*>(out) + tid;
        int f0 = spos[0];
#pragma unroll
        for (int j = 0; j < CHUNK; ++j) {
            int f1 = spos[j + 1];               // LDS (lgkmcnt only)
            for (int f = f0; f < f1; ++f)
                __builtin_nontemporal_store(xv[j], &out2[(size_t)f * (DCH / 2)]);
            f0 = f1;
        }
    }
}

extern "C" void kernel_launch(void* const* d_in, const int* in_sizes, int n_in,
                              void* d_out, int out_size, void* d_ws, size_t ws_size,
                              hipStream_t stream) {
    const float* x = (const float*)d_in[0];
    const float* p = (const float*)d_in[1];
    const int* b = (const int*)d_in[2];
    float* out = (float*)d_out;
    (void)d_ws; (void)ws_size;

    fused_kernel<<<NCHUNK, NTHR, 0, stream>>>(x, p, b, out);
}